// Round 4
// baseline (169.816 us; speedup 1.0000x reference)
//
#include <hip/hip_runtime.h>
#include <hip/hip_cooperative_groups.h>
#include <math.h>

namespace cg = cooperative_groups;

#define BATCH 8
#define H 256
#define W 256
#define NPIX (BATCH * H * W)
#define CT 4
#define NBLK 512   // = BATCH * (W/CT); also covers 2048 rows at 4 rows/block

__device__ __forceinline__ float bce_logits(float p, float t) {
    return fmaxf(p, 0.0f) - p * t + log1pf(expf(-fabsf(p)));
}

__global__ void __launch_bounds__(256, 2) fused_all(
        const float* __restrict__ target, const float* __restrict__ pred,
        float* __restrict__ g2, float* __restrict__ pmx,
        float* __restrict__ psb, float* __restrict__ psdb,
        float* __restrict__ out) {
    cg::grid_group grid = cg::this_grid();
    __shared__ float col[H][CT];          // 4 KB
    __shared__ float part[4][H][CT];      // 16 KB
    __shared__ float red[3][8];

    const int tid = threadIdx.x;
    const int wv = tid >> 6, l = tid & 63;

    // ---------- Phase A: row EDT (g^2); one wave per row, 4 rows/block ----------
    {
        const int r = blockIdx.x * 4 + wv;            // 0..2047
        const float* trow = target + (size_t)r * W;
        float t0 = trow[l], t1 = trow[l + 64], t2 = trow[l + 128], t3 = trow[l + 192];
        unsigned long long m0 = __ballot(t0 == 0.0f);
        unsigned long long m1 = __ballot(t1 == 0.0f);
        unsigned long long m2 = __ballot(t2 == 0.0f);
        unsigned long long m3 = __ballot(t3 == 0.0f);
        const int NEG = -(1 << 20), POS = 1 << 20;
        int hp0 = m0 ? (63 - __builtin_clzll(m0)) : NEG;
        int hp1 = m1 ? (64 + 63 - __builtin_clzll(m1)) : NEG;
        int hp2 = m2 ? (128 + 63 - __builtin_clzll(m2)) : NEG;
        int lp1 = m1 ? (64 + __builtin_ctzll(m1)) : POS;
        int lp2 = m2 ? (128 + __builtin_ctzll(m2)) : POS;
        int lp3 = m3 ? (192 + __builtin_ctzll(m3)) : POS;
        int pmaxv[4] = {NEG, hp0, max(hp0, hp1), max(max(hp0, hp1), hp2)};
        int sminv[4] = {min(lp1, min(lp2, lp3)), min(lp2, lp3), lp3, POS};
        unsigned long long mm[4] = {m0, m1, m2, m3};
        float* grow = g2 + (size_t)r * W;
        #pragma unroll
        for (int c = 0; c < 4; ++c) {
            unsigned long long mw = mm[c];
            int p = 64 * c + l;
            unsigned long long mlo = mw & ((2ull << l) - 1ull);   // bits <= l (l=63 ok)
            unsigned long long mhi = mw & (~0ull << l);           // bits >= l
            int best = POS;
            if (mlo) best = l - (63 - __builtin_clzll(mlo));
            if (mhi) best = min(best, __builtin_ctzll(mhi) - l);
            best = min(best, p - pmaxv[c]);
            best = min(best, sminv[c] - p);
            float d = (best > 255) ? 1e4f : (float)best;          // INF per reference
            grow[p] = d * d;
        }
    }

    grid.sync();

    // ---------- Phase B: column envelope + fused BCE; block -> (image, 4 cols) ----------
    const int b  = blockIdx.x >> 6;               // image
    const int w0 = (blockIdx.x & 63) * CT;        // column tile
    {
        const float* gb = g2 + (size_t)b * H * W + w0;
        *(float4*)&col[tid][0] = *(const float4*)(gb + (size_t)tid * W);
        __syncthreads();

        float acc[4][CT];
        #pragma unroll
        for (int j = 0; j < 4; ++j)
            #pragma unroll
            for (int c = 0; c < CT; ++c) acc[j][c] = 3.0e38f;

        const int k0 = wv << 6;
        for (int kk = 0; kk < 64; ++kk) {
            const int k = k0 + kk;
            float4 c4 = *(const float4*)&col[k][0];     // wave-uniform broadcast
            float d0 = (float)(l - k);
            #pragma unroll
            for (int j = 0; j < 4; ++j) {
                float dk  = d0 + (float)(64 * j);       // output row = l + 64j
                float dk2 = dk * dk;
                acc[j][0] = fminf(acc[j][0], c4.x + dk2);
                acc[j][1] = fminf(acc[j][1], c4.y + dk2);
                acc[j][2] = fminf(acc[j][2], c4.z + dk2);
                acc[j][3] = fminf(acc[j][3], c4.w + dk2);
            }
        }
        #pragma unroll
        for (int j = 0; j < 4; ++j)
            *(float4*)&part[wv][l + 64 * j][0] = *(float4*)&acc[j][0];
        __syncthreads();

        float4 r0 = *(const float4*)&part[0][tid][0];
        float4 r1 = *(const float4*)&part[1][tid][0];
        float4 r2 = *(const float4*)&part[2][tid][0];
        float4 r3 = *(const float4*)&part[3][tid][0];
        float dd0 = fminf(fminf(r0.x, r1.x), fminf(r2.x, r3.x));
        float dd1 = fminf(fminf(r0.y, r1.y), fminf(r2.y, r3.y));
        float dd2 = fminf(fminf(r0.z, r1.z), fminf(r2.z, r3.z));
        float dd3 = fminf(fminf(r0.w, r1.w), fminf(r2.w, r3.w));

        const size_t off = ((size_t)(b * H + tid)) * W + w0;
        const float4 p4 = *(const float4*)(pred + off);
        const float4 t4 = *(const float4*)(target + off);

        float mx = fmaxf(fmaxf(dd0, dd1), fmaxf(dd2, dd3));
        float b0 = bce_logits(p4.x, t4.x);
        float b1 = bce_logits(p4.y, t4.y);
        float b2 = bce_logits(p4.z, t4.z);
        float b3 = bce_logits(p4.w, t4.w);
        float sb  = (b0 + b1) + (b2 + b3);
        float sdb = (sqrtf(dd0) * b0 + sqrtf(dd1) * b1) + (sqrtf(dd2) * b2 + sqrtf(dd3) * b3);

        #pragma unroll
        for (int o = 32; o > 0; o >>= 1) {
            mx  = fmaxf(mx, __shfl_down(mx, o, 64));
            sb  += __shfl_down(sb, o, 64);
            sdb += __shfl_down(sdb, o, 64);
        }
        if (l == 0) { red[0][wv] = mx; red[1][wv] = sb; red[2][wv] = sdb; }
        __syncthreads();
        if (tid == 0) {
            pmx [blockIdx.x] = fmaxf(fmaxf(red[0][0], red[0][1]), fmaxf(red[0][2], red[0][3]));
            psb [blockIdx.x] = (red[1][0] + red[1][1]) + (red[1][2] + red[1][3]);
            psdb[blockIdx.x] = (red[2][0] + red[2][1]) + (red[2][2] + red[2][3]);
        }
    }

    grid.sync();

    // ---------- Phase C: block 0 combines 512 partials -> scalar ----------
    if (blockIdx.x == 0) {
        const int img = tid >> 5, j = tid & 31;       // 8 images x 32 threads
        const int e0 = (img << 6) + j, e1 = e0 + 32;
        float mx  = fmaxf(pmx[e0], pmx[e1]);
        float sb  = psb[e0] + psb[e1];
        float sdb = psdb[e0] + psdb[e1];
        #pragma unroll
        for (int o = 16; o > 0; o >>= 1) {            // width-32 groups stay per-image
            mx  = fmaxf(mx, __shfl_down(mx, o, 32));
            sb  += __shfl_down(sb, o, 32);
            sdb += __shfl_down(sdb, o, 32);
        }
        __shared__ float cimg[8], simg[8];
        if (j == 0) {
            cimg[img] = sdb / (sqrtf(mx) + 1e-7f);    // sqrt commutes with max
            simg[img] = sb;
        }
        __syncthreads();
        if (tid == 0) {
            float tot = 0.0f;
            #pragma unroll
            for (int i = 0; i < 8; ++i) tot += simg[i] + cimg[i];
            out[0] = tot * (1.0f / (float)NPIX);
        }
    }
}

extern "C" void kernel_launch(void* const* d_in, const int* in_sizes, int n_in,
                              void* d_out, int out_size, void* d_ws, size_t ws_size,
                              hipStream_t stream) {
    const float* pred   = (const float*)d_in[0];
    const float* target = (const float*)d_in[1];

    float* g2   = (float*)d_ws;                                   // 8 MB
    float* pmx  = (float*)((char*)d_ws + (size_t)NPIX * sizeof(float));
    float* psb  = pmx + NBLK;
    float* psdb = psb + NBLK;
    float* outp = (float*)d_out;

    void* args[] = {(void*)&target, (void*)&pred, (void*)&g2,
                    (void*)&pmx, (void*)&psb, (void*)&psdb, (void*)&outp};
    hipLaunchCooperativeKernel((void*)fused_all, dim3(NBLK), dim3(256), args, 0, stream);
}

// Round 5
// 90.275 us; speedup vs baseline: 1.8811x; 1.8811x over previous
//
#include <hip/hip_runtime.h>
#include <math.h>

#define BATCH 8
#define H 256
#define W 256
#define NPIX (BATCH * H * W)
#define CT 4      // columns per block -> 512 blocks = 2/CU
#define NBLK 512  // BATCH * (W/CT)

__device__ __forceinline__ float bce_logits(float p, float t) {
    return fmaxf(p, 0.0f) - p * t + log1pf(expf(-fabsf(p)));
}

// One kernel does everything except the final 512->1 combine.
// Block = (image b, 4-column tile w0). No inter-block dependencies.
__global__ void __launch_bounds__(256, 2) edt_bce_main(
        const float* __restrict__ target, const float* __restrict__ pred,
        float* __restrict__ pmx, float* __restrict__ psb, float* __restrict__ psdb) {
    __shared__ unsigned long long masks[H][4];   // 8 KB: zero-pixel bitmask per row
    __shared__ float col[H][CT];                 // 4 KB: g^2 for this block's columns
    __shared__ float part[4][H][CT];             // 16 KB: per-wave envelope partials
    __shared__ float red[3][4];

    const int tid = threadIdx.x;
    const int wv = tid >> 6, l = tid & 63;
    const int b  = blockIdx.x >> 6;               // image
    const int w0 = (blockIdx.x & 63) * CT;        // column tile base

    // ---- Phase 1: build the image's zero-masks (each wave: 64 rows) ----
    {
        const float* img = target + (size_t)b * H * W;
        for (int rr = 0; rr < 64; ++rr) {
            const int r = (wv << 6) + rr;
            const float* trow = img + (size_t)r * W;
            unsigned long long m0 = __ballot(trow[l      ] == 0.0f);
            unsigned long long m1 = __ballot(trow[l +  64] == 0.0f);
            unsigned long long m2 = __ballot(trow[l + 128] == 0.0f);
            unsigned long long m3 = __ballot(trow[l + 192] == 0.0f);
            if (l < 4) {
                unsigned long long m = (l == 0) ? m0 : (l == 1) ? m1 : (l == 2) ? m2 : m3;
                masks[r][l] = m;
            }
        }
    }
    __syncthreads();

    // ---- Phase 2: row-EDT squared at this block's 4 columns (thread = row) ----
    {
        unsigned long long mw0 = masks[tid][0], mw1 = masks[tid][1];
        unsigned long long mw2 = masks[tid][2], mw3 = masks[tid][3];
        unsigned long long mw[4] = {mw0, mw1, mw2, mw3};
        #pragma unroll
        for (int c = 0; c < CT; ++c) {
            const int p = w0 + c;
            int best = 1 << 20;
            #pragma unroll
            for (int w = 0; w < 4; ++w) {
                const int rel = p - (w << 6);
                const unsigned long long m = mw[w];
                unsigned long long mlo = (rel < 0)  ? 0ull
                                       : (rel >= 63) ? m : (m & ((2ull << rel) - 1ull));
                unsigned long long mhi = (rel <= 0) ? m
                                       : (rel > 63)  ? 0ull : (m & (~0ull << rel));
                if (mlo) best = min(best, rel - (63 - __builtin_clzll(mlo)));
                if (mhi) best = min(best, __builtin_ctzll(mhi) - rel);
            }
            float d = (best > 255) ? 1e4f : (float)best;   // INF per reference
            col[tid][c] = d * d;
        }
    }
    __syncthreads();

    // ---- Phase 3: column envelope (each wave: disjoint 64-k chunk) + BCE ----
    float acc[4][CT];
    #pragma unroll
    for (int j = 0; j < 4; ++j)
        #pragma unroll
        for (int c = 0; c < CT; ++c) acc[j][c] = 3.0e38f;

    const int k0 = wv << 6;
    for (int kk = 0; kk < 64; ++kk) {
        const int k = k0 + kk;
        float4 c4 = *(const float4*)&col[k][0];    // wave-uniform broadcast
        float d0 = (float)(l - k);
        #pragma unroll
        for (int j = 0; j < 4; ++j) {
            float dk  = d0 + (float)(64 * j);      // output row = l + 64j
            float dk2 = dk * dk;
            acc[j][0] = fminf(acc[j][0], c4.x + dk2);
            acc[j][1] = fminf(acc[j][1], c4.y + dk2);
            acc[j][2] = fminf(acc[j][2], c4.z + dk2);
            acc[j][3] = fminf(acc[j][3], c4.w + dk2);
        }
    }
    #pragma unroll
    for (int j = 0; j < 4; ++j)
        *(float4*)&part[wv][l + 64 * j][0] = *(float4*)&acc[j][0];
    __syncthreads();

    float4 r0 = *(const float4*)&part[0][tid][0];
    float4 r1 = *(const float4*)&part[1][tid][0];
    float4 r2 = *(const float4*)&part[2][tid][0];
    float4 r3 = *(const float4*)&part[3][tid][0];
    float dd0 = fminf(fminf(r0.x, r1.x), fminf(r2.x, r3.x));
    float dd1 = fminf(fminf(r0.y, r1.y), fminf(r2.y, r3.y));
    float dd2 = fminf(fminf(r0.z, r1.z), fminf(r2.z, r3.z));
    float dd3 = fminf(fminf(r0.w, r1.w), fminf(r2.w, r3.w));

    const size_t off = ((size_t)(b * H + tid)) * W + w0;
    const float4 p4 = *(const float4*)(pred + off);
    const float4 t4 = *(const float4*)(target + off);

    float mx = fmaxf(fmaxf(dd0, dd1), fmaxf(dd2, dd3));    // per-thread max d2
    float b0 = bce_logits(p4.x, t4.x);
    float b1 = bce_logits(p4.y, t4.y);
    float b2 = bce_logits(p4.z, t4.z);
    float b3 = bce_logits(p4.w, t4.w);
    float sb  = (b0 + b1) + (b2 + b3);
    float sdb = (sqrtf(dd0) * b0 + sqrtf(dd1) * b1) + (sqrtf(dd2) * b2 + sqrtf(dd3) * b3);

    #pragma unroll
    for (int o = 32; o > 0; o >>= 1) {
        mx  = fmaxf(mx, __shfl_down(mx, o, 64));
        sb  += __shfl_down(sb, o, 64);
        sdb += __shfl_down(sdb, o, 64);
    }
    if (l == 0) { red[0][wv] = mx; red[1][wv] = sb; red[2][wv] = sdb; }
    __syncthreads();
    if (tid == 0) {
        pmx [blockIdx.x] = fmaxf(fmaxf(red[0][0], red[0][1]), fmaxf(red[0][2], red[0][3]));
        psb [blockIdx.x] = (red[1][0] + red[1][1]) + (red[1][2] + red[1][3]);
        psdb[blockIdx.x] = (red[2][0] + red[2][1]) + (red[2][2] + red[2][3]);
    }
}

// Tiny combine: 512 partials -> scalar. Images are contiguous 64-block runs.
__global__ void final_reduce(const float* __restrict__ pmx, const float* __restrict__ psb,
                             const float* __restrict__ psdb, float* __restrict__ out) {
    const int tid = threadIdx.x;
    const int img = tid >> 5, j = tid & 31;        // 8 images x 32 threads
    const int e0 = (img << 6) + j, e1 = e0 + 32;
    float mx  = fmaxf(pmx[e0], pmx[e1]);
    float sb  = psb[e0] + psb[e1];
    float sdb = psdb[e0] + psdb[e1];
    #pragma unroll
    for (int o = 16; o > 0; o >>= 1) {             // width-32 groups stay per-image
        mx  = fmaxf(mx, __shfl_down(mx, o, 32));
        sb  += __shfl_down(sb, o, 32);
        sdb += __shfl_down(sdb, o, 32);
    }
    __shared__ float cimg[8], simg[8];
    if (j == 0) {
        cimg[img] = sdb / (sqrtf(mx) + 1e-7f);     // sqrt commutes with max
        simg[img] = sb;
    }
    __syncthreads();
    if (tid == 0) {
        float tot = 0.0f;
        #pragma unroll
        for (int i = 0; i < 8; ++i) tot += simg[i] + cimg[i];
        out[0] = tot * (1.0f / (float)NPIX);
    }
}

extern "C" void kernel_launch(void* const* d_in, const int* in_sizes, int n_in,
                              void* d_out, int out_size, void* d_ws, size_t ws_size,
                              hipStream_t stream) {
    const float* pred   = (const float*)d_in[0];
    const float* target = (const float*)d_in[1];

    float* pmx  = (float*)d_ws;
    float* psb  = pmx + NBLK;
    float* psdb = psb + NBLK;

    edt_bce_main<<<NBLK, 256, 0, stream>>>(target, pred, pmx, psb, psdb);
    final_reduce<<<1, 256, 0, stream>>>(pmx, psb, psdb, (float*)d_out);
}

// Round 6
// 75.396 us; speedup vs baseline: 2.2523x; 1.1973x over previous
//
#include <hip/hip_runtime.h>
#include <math.h>

#define BATCH 8
#define H 256
#define W 256
#define NPIX (BATCH * H * W)
#define CT 4      // columns per block -> 512 blocks = 2/CU
#define NBLK 512  // BATCH * (W/CT)
#define NROWS (BATCH * H)

__device__ __forceinline__ float bce_logits(float p, float t) {
    return fmaxf(p, 0.0f) - p * t + log1pf(expf(-fabsf(p)));
}

// K1: zero-pixel bitmasks per row. 4 rows/block (one wave each), 512 blocks.
// Output: masks[row][4] ull = 64 KB total (L2-resident for K2).
__global__ void __launch_bounds__(256) make_masks(const float* __restrict__ target,
                                                  unsigned long long* __restrict__ masks) {
    const int wv = threadIdx.x >> 6, l = threadIdx.x & 63;
    const int r = blockIdx.x * 4 + wv;             // 0..2047
    const float* trow = target + (size_t)r * W;
    float t0 = trow[l], t1 = trow[l + 64], t2 = trow[l + 128], t3 = trow[l + 192];
    unsigned long long m0 = __ballot(t0 == 0.0f);
    unsigned long long m1 = __ballot(t1 == 0.0f);
    unsigned long long m2 = __ballot(t2 == 0.0f);
    unsigned long long m3 = __ballot(t3 == 0.0f);
    if (l < 4) {
        unsigned long long m = (l == 0) ? m0 : (l == 1) ? m1 : (l == 2) ? m2 : m3;
        masks[(size_t)r * 4 + l] = m;
    }
}

// K2: per-row g^2 from masks (registers) -> column envelope -> fused BCE.
// Block = (image b, 4-column tile w0). All global loads issued up front.
__global__ void __launch_bounds__(256, 2) edt_bce_main(
        const unsigned long long* __restrict__ masks, const float* __restrict__ pred,
        const float* __restrict__ target,
        float* __restrict__ pmx, float* __restrict__ psb, float* __restrict__ psdb) {
    __shared__ float col[H][CT];                 // 4 KB: g^2 for this block's columns
    __shared__ float part[4][H][CT];             // 16 KB: per-wave envelope partials
    __shared__ float red[3][4];

    const int tid = threadIdx.x;
    const int wv = tid >> 6, l = tid & 63;
    const int b  = blockIdx.x >> 6;               // image
    const int w0 = (blockIdx.x & 63) * CT;        // column tile base

    // ---- Issue ALL global loads first; compute hides their latency ----
    const size_t off = ((size_t)(b * H + tid)) * W + w0;
    const float4 p4 = *(const float4*)(pred + off);      // consumed at the very end
    const float4 t4 = *(const float4*)(target + off);
    const unsigned long long* mrow = masks + ((size_t)(b * H + tid)) * 4;
    unsigned long long mw0 = mrow[0], mw1 = mrow[1], mw2 = mrow[2], mw3 = mrow[3];

    // ---- Phase 1: row-EDT squared at this block's 4 columns (thread = row) ----
    {
        unsigned long long mw[4] = {mw0, mw1, mw2, mw3};
        #pragma unroll
        for (int c = 0; c < CT; ++c) {
            const int p = w0 + c;
            int best = 1 << 20;
            #pragma unroll
            for (int w = 0; w < 4; ++w) {
                const int rel = p - (w << 6);
                const unsigned long long m = mw[w];
                unsigned long long mlo = (rel < 0)  ? 0ull
                                       : (rel >= 63) ? m : (m & ((2ull << rel) - 1ull));
                unsigned long long mhi = (rel <= 0) ? m
                                       : (rel > 63)  ? 0ull : (m & (~0ull << rel));
                if (mlo) best = min(best, rel - (63 - __builtin_clzll(mlo)));
                if (mhi) best = min(best, __builtin_ctzll(mhi) - rel);
            }
            float d = (best > 255) ? 1e4f : (float)best;   // INF per reference
            col[tid][c] = d * d;
        }
    }
    __syncthreads();

    // ---- Phase 2: column envelope (each wave: disjoint 64-k chunk) ----
    float acc[4][CT];
    #pragma unroll
    for (int j = 0; j < 4; ++j)
        #pragma unroll
        for (int c = 0; c < CT; ++c) acc[j][c] = 3.0e38f;

    const int k0 = wv << 6;
    #pragma unroll 4
    for (int kk = 0; kk < 64; ++kk) {
        const int k = k0 + kk;
        float4 c4 = *(const float4*)&col[k][0];    // wave-uniform broadcast
        float d0 = (float)(l - k);
        #pragma unroll
        for (int j = 0; j < 4; ++j) {
            float dk  = d0 + (float)(64 * j);      // output row = l + 64j
            float dk2 = dk * dk;
            acc[j][0] = fminf(acc[j][0], c4.x + dk2);
            acc[j][1] = fminf(acc[j][1], c4.y + dk2);
            acc[j][2] = fminf(acc[j][2], c4.z + dk2);
            acc[j][3] = fminf(acc[j][3], c4.w + dk2);
        }
    }
    #pragma unroll
    for (int j = 0; j < 4; ++j)
        *(float4*)&part[wv][l + 64 * j][0] = *(float4*)&acc[j][0];
    __syncthreads();

    // ---- Phase 3: combine wave partials, fused BCE epilogue ----
    float4 r0 = *(const float4*)&part[0][tid][0];
    float4 r1 = *(const float4*)&part[1][tid][0];
    float4 r2 = *(const float4*)&part[2][tid][0];
    float4 r3 = *(const float4*)&part[3][tid][0];
    float dd0 = fminf(fminf(r0.x, r1.x), fminf(r2.x, r3.x));
    float dd1 = fminf(fminf(r0.y, r1.y), fminf(r2.y, r3.y));
    float dd2 = fminf(fminf(r0.z, r1.z), fminf(r2.z, r3.z));
    float dd3 = fminf(fminf(r0.w, r1.w), fminf(r2.w, r3.w));

    float mx = fmaxf(fmaxf(dd0, dd1), fmaxf(dd2, dd3));    // per-thread max d2
    float b0 = bce_logits(p4.x, t4.x);
    float b1 = bce_logits(p4.y, t4.y);
    float b2 = bce_logits(p4.z, t4.z);
    float b3 = bce_logits(p4.w, t4.w);
    float sb  = (b0 + b1) + (b2 + b3);
    float sdb = (sqrtf(dd0) * b0 + sqrtf(dd1) * b1) + (sqrtf(dd2) * b2 + sqrtf(dd3) * b3);

    #pragma unroll
    for (int o = 32; o > 0; o >>= 1) {
        mx  = fmaxf(mx, __shfl_down(mx, o, 64));
        sb  += __shfl_down(sb, o, 64);
        sdb += __shfl_down(sdb, o, 64);
    }
    if (l == 0) { red[0][wv] = mx; red[1][wv] = sb; red[2][wv] = sdb; }
    __syncthreads();
    if (tid == 0) {
        pmx [blockIdx.x] = fmaxf(fmaxf(red[0][0], red[0][1]), fmaxf(red[0][2], red[0][3]));
        psb [blockIdx.x] = (red[1][0] + red[1][1]) + (red[1][2] + red[1][3]);
        psdb[blockIdx.x] = (red[2][0] + red[2][1]) + (red[2][2] + red[2][3]);
    }
}

// K3: tiny combine: 512 partials -> scalar. Images are contiguous 64-block runs.
__global__ void final_reduce(const float* __restrict__ pmx, const float* __restrict__ psb,
                             const float* __restrict__ psdb, float* __restrict__ out) {
    const int tid = threadIdx.x;
    const int img = tid >> 5, j = tid & 31;        // 8 images x 32 threads
    const int e0 = (img << 6) + j, e1 = e0 + 32;
    float mx  = fmaxf(pmx[e0], pmx[e1]);
    float sb  = psb[e0] + psb[e1];
    float sdb = psdb[e0] + psdb[e1];
    #pragma unroll
    for (int o = 16; o > 0; o >>= 1) {             // width-32 groups stay per-image
        mx  = fmaxf(mx, __shfl_down(mx, o, 32));
        sb  += __shfl_down(sb, o, 32);
        sdb += __shfl_down(sdb, o, 32);
    }
    __shared__ float cimg[8], simg[8];
    if (j == 0) {
        cimg[img] = sdb / (sqrtf(mx) + 1e-7f);     // sqrt commutes with max
        simg[img] = sb;
    }
    __syncthreads();
    if (tid == 0) {
        float tot = 0.0f;
        #pragma unroll
        for (int i = 0; i < 8; ++i) tot += simg[i] + cimg[i];
        out[0] = tot * (1.0f / (float)NPIX);
    }
}

extern "C" void kernel_launch(void* const* d_in, const int* in_sizes, int n_in,
                              void* d_out, int out_size, void* d_ws, size_t ws_size,
                              hipStream_t stream) {
    const float* pred   = (const float*)d_in[0];
    const float* target = (const float*)d_in[1];

    unsigned long long* masks = (unsigned long long*)d_ws;        // 64 KB
    float* pmx  = (float*)((char*)d_ws + (size_t)NROWS * 4 * sizeof(unsigned long long));
    float* psb  = pmx + NBLK;
    float* psdb = psb + NBLK;

    make_masks<<<NROWS / 4, 256, 0, stream>>>(target, masks);
    edt_bce_main<<<NBLK, 256, 0, stream>>>(masks, pred, target, pmx, psb, psdb);
    final_reduce<<<1, 256, 0, stream>>>(pmx, psb, psdb, (float*)d_out);
}

// Round 7
// 74.510 us; speedup vs baseline: 2.2791x; 1.0119x over previous
//
#include <hip/hip_runtime.h>
#include <math.h>

#define BATCH 8
#define H 256
#define W 256
#define NPIX (BATCH * H * W)
#define CT 2       // columns per block -> 1024 blocks = 4/CU
#define NBLK (BATCH * (W / CT))   // 1024
#define NROWS (BATCH * H)

__device__ __forceinline__ float bce_logits(float p, float t) {
    return fmaxf(p, 0.0f) - p * t + log1pf(expf(-fabsf(p)));
}

// K1: zero-pixel bitmasks per row. 4 rows/block (one wave each), 512 blocks.
// Output: masks[row][4] ull = 64 KB total (L2/IC-resident for K2).
__global__ void __launch_bounds__(256) make_masks(const float* __restrict__ target,
                                                  unsigned long long* __restrict__ masks) {
    const int wv = threadIdx.x >> 6, l = threadIdx.x & 63;
    const int r = blockIdx.x * 4 + wv;             // 0..2047
    const float* trow = target + (size_t)r * W;
    float t0 = trow[l], t1 = trow[l + 64], t2 = trow[l + 128], t3 = trow[l + 192];
    unsigned long long m0 = __ballot(t0 == 0.0f);
    unsigned long long m1 = __ballot(t1 == 0.0f);
    unsigned long long m2 = __ballot(t2 == 0.0f);
    unsigned long long m3 = __ballot(t3 == 0.0f);
    if (l < 4) {
        unsigned long long m = (l == 0) ? m0 : (l == 1) ? m1 : (l == 2) ? m2 : m3;
        masks[(size_t)r * 4 + l] = m;
    }
}

// K2: thread = output row i; block = (image, 2 columns). One data barrier.
// Row-EDT g^2 from masks (registers) -> full-k envelope (wave-uniform LDS
// broadcast, fma+min3) -> fused BCE epilogue -> per-block partials.
__global__ void edt_bce_main(
        const unsigned long long* __restrict__ masks, const float* __restrict__ pred,
        const float* __restrict__ target,
        float* __restrict__ pmx, float* __restrict__ psb, float* __restrict__ psdb) {
    __shared__ float2 colv[H];                   // 2 KB: g^2 for this block's 2 columns
    __shared__ float red[3][4];

    const int tid = threadIdx.x;                 // = row index i and k-writer index
    const int wv = tid >> 6, l = tid & 63;
    const int b  = blockIdx.x >> 7;              // image
    const int w0 = (blockIdx.x & 127) * CT;      // column tile base

    // ---- Issue all global loads up front (consumed much later) ----
    const size_t off = ((size_t)(b * H + tid)) * W + w0;
    const float2 p2 = *(const float2*)(pred + off);
    const float2 t2 = *(const float2*)(target + off);
    const unsigned long long* mrow = masks + ((size_t)(b * H + tid)) * 4;
    unsigned long long mw0 = mrow[0], mw1 = mrow[1], mw2 = mrow[2], mw3 = mrow[3];

    // ---- Phase 1: row-EDT squared at this block's 2 columns (thread = row) ----
    {
        unsigned long long mw[4] = {mw0, mw1, mw2, mw3};
        float g[CT];
        #pragma unroll
        for (int c = 0; c < CT; ++c) {
            const int p = w0 + c;
            int best = 1 << 20;
            #pragma unroll
            for (int w = 0; w < 4; ++w) {
                const int rel = p - (w << 6);
                const unsigned long long m = mw[w];
                unsigned long long mlo = (rel < 0)  ? 0ull
                                       : (rel >= 63) ? m : (m & ((2ull << rel) - 1ull));
                unsigned long long mhi = (rel <= 0) ? m
                                       : (rel > 63)  ? 0ull : (m & (~0ull << rel));
                if (mlo) best = min(best, rel - (63 - __builtin_clzll(mlo)));
                if (mhi) best = min(best, __builtin_ctzll(mhi) - rel);
            }
            float d = (best > 255) ? 1e4f : (float)best;   // INF per reference
            g[c] = d * d;
        }
        colv[tid] = make_float2(g[0], g[1]);
    }
    __syncthreads();

    // ---- Phase 2: envelope d2[i] = min_k g2[k] + (i-k)^2, all k per thread ----
    // fmaf(d,d,g2) is exact here (all integers < 2^24) == reference arithmetic.
    const float fi = (float)tid;
    float acc0 = 3.0e38f, acc1 = 3.0e38f;
    float fk = 0.0f;
    #pragma unroll 4
    for (int k = 0; k < H; k += 2) {
        float2 cA = colv[k];                     // wave-uniform broadcast reads
        float2 cB = colv[k + 1];
        float dA = fi - fk, dB = dA - 1.0f;
        acc0 = fminf(acc0, fminf(fmaf(dA, dA, cA.x), fmaf(dB, dB, cB.x)));  // v_min3
        acc1 = fminf(acc1, fminf(fmaf(dA, dA, cA.y), fmaf(dB, dB, cB.y)));
        fk += 2.0f;
    }

    // ---- Epilogue: fused BCE + per-block partial reduction ----
    float mx = fmaxf(acc0, acc1);                // per-thread max d2
    float b0 = bce_logits(p2.x, t2.x);
    float b1 = bce_logits(p2.y, t2.y);
    float sb  = b0 + b1;
    float sdb = sqrtf(acc0) * b0 + sqrtf(acc1) * b1;

    #pragma unroll
    for (int o = 32; o > 0; o >>= 1) {
        mx  = fmaxf(mx, __shfl_down(mx, o, 64));
        sb  += __shfl_down(sb, o, 64);
        sdb += __shfl_down(sdb, o, 64);
    }
    if (l == 0) { red[0][wv] = mx; red[1][wv] = sb; red[2][wv] = sdb; }
    __syncthreads();
    if (tid == 0) {
        pmx [blockIdx.x] = fmaxf(fmaxf(red[0][0], red[0][1]), fmaxf(red[0][2], red[0][3]));
        psb [blockIdx.x] = (red[1][0] + red[1][1]) + (red[1][2] + red[1][3]);
        psdb[blockIdx.x] = (red[2][0] + red[2][1]) + (red[2][2] + red[2][3]);
    }
}

// K3: 1024 partials -> scalar. Images are contiguous 128-block runs.
__global__ void final_reduce(const float* __restrict__ pmx, const float* __restrict__ psb,
                             const float* __restrict__ psdb, float* __restrict__ out) {
    const int tid = threadIdx.x;
    const int img = tid >> 5, j = tid & 31;        // 8 images x 32 threads
    const int base = (img << 7) + j;
    float mx = 0.0f, sb = 0.0f, sdb = 0.0f;
    #pragma unroll
    for (int q = 0; q < 4; ++q) {
        const int e = base + 32 * q;
        mx  = fmaxf(mx, pmx[e]);
        sb  += psb[e];
        sdb += psdb[e];
    }
    #pragma unroll
    for (int o = 16; o > 0; o >>= 1) {             // width-32 groups stay per-image
        mx  = fmaxf(mx, __shfl_down(mx, o, 32));
        sb  += __shfl_down(sb, o, 32);
        sdb += __shfl_down(sdb, o, 32);
    }
    __shared__ float cimg[8], simg[8];
    if (j == 0) {
        cimg[img] = sdb / (sqrtf(mx) + 1e-7f);     // sqrt commutes with max
        simg[img] = sb;
    }
    __syncthreads();
    if (tid == 0) {
        float tot = 0.0f;
        #pragma unroll
        for (int i = 0; i < 8; ++i) tot += simg[i] + cimg[i];
        out[0] = tot * (1.0f / (float)NPIX);
    }
}

extern "C" void kernel_launch(void* const* d_in, const int* in_sizes, int n_in,
                              void* d_out, int out_size, void* d_ws, size_t ws_size,
                              hipStream_t stream) {
    const float* pred   = (const float*)d_in[0];
    const float* target = (const float*)d_in[1];

    unsigned long long* masks = (unsigned long long*)d_ws;        // 64 KB
    float* pmx  = (float*)((char*)d_ws + (size_t)NROWS * 4 * sizeof(unsigned long long));
    float* psb  = pmx + NBLK;
    float* psdb = psb + NBLK;

    make_masks<<<NROWS / 4, 256, 0, stream>>>(target, masks);
    edt_bce_main<<<NBLK, 256, 0, stream>>>(masks, pred, target, pmx, psb, psdb);
    final_reduce<<<1, 256, 0, stream>>>(pmx, psb, psdb, (float*)d_out);
}